// Round 4
// baseline (250.542 us; speedup 1.0000x reference)
//
#include <hip/hip_runtime.h>
#include <hip/hip_bf16.h>

#define Ls 256
#define Kk 9
#define Bb 512

typedef short s16x8 __attribute__((ext_vector_type(8)));
typedef float f32x4 __attribute__((ext_vector_type(4)));

__device__ __forceinline__ unsigned short f2bf(float f) {
    __hip_bfloat16 h = __float2bfloat16(f);
    return *reinterpret_cast<unsigned short*>(&h);
}

// XOR swizzle: spreads 16 consecutive rows 2-way (free) on reads AND makes
// row-groups {c,c+4,c+8,c+12} (epilogue b16 stores) hit 4 distinct 16B slots.
#define SWZ(row) (((((row)&7)<<4)) ^ ((((row)&8))<<2))

// ---- weight prep: pack w1/w2/w3/wd into bf16 MFMA B-fragments ----
__global__ __launch_bounds__(256) void kw_prep(
    const float* __restrict__ w1, const float* __restrict__ w2, const float* __restrict__ w3,
    const float* __restrict__ wd, uint4* __restrict__ wfrag)
{
    const int gid = blockIdx.x * 256 + threadIdx.x;
    const int frag = gid >> 6;
    const int lane = gid & 63;
    if (frag >= 196) return;
    const int kb = (lane >> 4) * 8;
    const int nl = lane & 15;
    float v[8];
    if (frag < 48) {
        int nt = frag & 3, kc = (frag >> 2) & 3, t = frag >> 4;
        int n = nt * 16 + nl;
        #pragma unroll
        for (int j = 0; j < 8; ++j) v[j] = w1[(t * 128 + kc * 32 + kb + j) * 64 + n];
    } else if (frag < 96) {
        int f = frag - 48; int nt = f & 7, kc = (f >> 3) & 1, t = f >> 4;
        int n = nt * 16 + nl;
        #pragma unroll
        for (int j = 0; j < 8; ++j) v[j] = w2[(t * 64 + kc * 32 + kb + j) * 128 + n];
    } else if (frag < 192) {
        int f = frag - 96; int nt = f & 7, kc = (f >> 3) & 3, t = f >> 5;
        int n = nt * 16 + nl;
        #pragma unroll
        for (int j = 0; j < 8; ++j) v[j] = w3[(t * 128 + kc * 32 + kb + j) * 128 + n];
    } else {
        int kc = frag - 192;
        #pragma unroll
        for (int j = 0; j < 8; ++j) v[j] = (nl < Kk) ? wd[(kc * 32 + kb + j) * Kk + nl] : 0.f;
    }
    uint4 o;
    o.x = (unsigned)f2bf(v[0]) | ((unsigned)f2bf(v[1]) << 16);
    o.y = (unsigned)f2bf(v[2]) | ((unsigned)f2bf(v[3]) << 16);
    o.z = (unsigned)f2bf(v[4]) | ((unsigned)f2bf(v[5]) << 16);
    o.w = (unsigned)f2bf(v[6]) | ((unsigned)f2bf(v[7]) << 16);
    wfrag[frag * 64 + lane] = o;
}

// ---- fused embed + conv1 + conv2 + conv3(dil2) + dense(MFMA) ----
#define X1_OFF  20992
#define X3_OFF  20992
#define SMEM_BYTES (20992 + 64 * 256)   // 37376 -> 4 blocks/CU

__global__ __launch_bounds__(256, 4) void kmain(
    const int* __restrict__ text, const float* __restrict__ embed,
    const uint4* __restrict__ wfrag,
    const float* __restrict__ b1, const float* __restrict__ b2, const float* __restrict__ b3,
    const float* __restrict__ bd,
    float* __restrict__ logits, float* __restrict__ logitsT)
{
    __shared__ __align__(16) char smem[SMEM_BYTES];
    const int b = blockIdx.y, l0 = blockIdx.x * 64;
    const int tid = threadIdx.x;
    const int lane = tid & 63, wv = tid >> 6;
    const int nl = lane & 15, kg = lane >> 4;

    for (int it = tid; it < 96; it += 256) {
        char* p;
        if (it < 32)       p = smem + it * 8;
        else if (it < 64)  p = smem + 81 * 256 + (it - 32) * 8;
        else if (it < 80)  p = smem + X1_OFF + (it - 64) * 8;
        else               p = smem + X1_OFF + 81 * 128 + (it - 80) * 8;
        *(uint2*)p = make_uint2(0u, 0u);
    }
    for (int it = tid; it < 80 * 32; it += 256) {
        const int row = (it >> 5) + 1;      // 1..80
        const int c4  = it & 31;
        const int pos = l0 - 9 + row;
        uint2 val = make_uint2(0u, 0u);
        if (pos >= 0 && pos < Ls) {
            const int tok = text[b * Ls + pos];
            const float4 e = ((const float4*)embed)[tok * 32 + c4];
            val.x = (unsigned)f2bf(e.x) | ((unsigned)f2bf(e.y) << 16);
            val.y = (unsigned)f2bf(e.z) | ((unsigned)f2bf(e.w) << 16);
        }
        int addr = row * 256 + c4 * 8;
        addr ^= SWZ(row);
        *(uint2*)(smem + addr) = val;
    }
    __syncthreads();

    // ---- conv1: M=80(5 tiles), N=64, K=3 x 128
    {
        f32x4 acc[5];
        #pragma unroll
        for (int mt = 0; mt < 5; ++mt) acc[mt] = (f32x4)0.f;
        #pragma unroll
        for (int t = 0; t < 3; ++t) {
            #pragma unroll
            for (int kc = 0; kc < 4; ++kc) {
                const s16x8 bf = *(const s16x8*)(wfrag + ((t * 4 + kc) * 4 + wv) * 64 + lane);
                #pragma unroll
                for (int mt = 0; mt < 5; ++mt) {
                    const int row = mt * 16 + nl + t;
                    int addr = row * 256 + kc * 64 + kg * 16;
                    addr ^= SWZ(row);
                    const s16x8 a = *(const s16x8*)(smem + addr);
                    acc[mt] = __builtin_amdgcn_mfma_f32_16x16x32_bf16(a, bf, acc[mt], 0, 0, 0);
                }
            }
        }
        const float bias = b1[wv * 16 + nl];
        #pragma unroll
        for (int mt = 0; mt < 5; ++mt) {
            #pragma unroll
            for (int r = 0; r < 4; ++r) {
                const int i = mt * 16 + kg * 4 + r;
                const int pos = l0 - 8 + i;
                float v = fmaxf(acc[mt][r] + bias, 0.f);
                if (pos < 0 || pos >= Ls) v = 0.f;
                const int row = i + 1;
                int addr = X1_OFF + row * 128 + (wv * 16 + nl) * 2;
                addr ^= SWZ(row);
                *(unsigned short*)(smem + addr) = f2bf(v);
            }
        }
    }
    __syncthreads();

    // ---- conv2: M=80, N=128, K=3 x 64
    {
        f32x4 acc[5][2];
        #pragma unroll
        for (int mt = 0; mt < 5; ++mt) { acc[mt][0] = (f32x4)0.f; acc[mt][1] = (f32x4)0.f; }
        #pragma unroll
        for (int t = 0; t < 3; ++t) {
            #pragma unroll
            for (int kc = 0; kc < 2; ++kc) {
                const s16x8 bf0 = *(const s16x8*)(wfrag + (48 + (t * 2 + kc) * 8 + wv) * 64 + lane);
                const s16x8 bf1 = *(const s16x8*)(wfrag + (48 + (t * 2 + kc) * 8 + wv + 4) * 64 + lane);
                #pragma unroll
                for (int mt = 0; mt < 5; ++mt) {
                    const int row = mt * 16 + nl + t;
                    int addr = X1_OFF + row * 128 + kc * 64 + kg * 16;
                    addr ^= SWZ(row);
                    const s16x8 a = *(const s16x8*)(smem + addr);
                    acc[mt][0] = __builtin_amdgcn_mfma_f32_16x16x32_bf16(a, bf0, acc[mt][0], 0, 0, 0);
                    acc[mt][1] = __builtin_amdgcn_mfma_f32_16x16x32_bf16(a, bf1, acc[mt][1], 0, 0, 0);
                }
            }
        }
        const float bs0 = b2[wv * 16 + nl], bs1 = b2[(wv + 4) * 16 + nl];
        #pragma unroll
        for (int mt = 0; mt < 5; ++mt) {
            #pragma unroll
            for (int r = 0; r < 4; ++r) {
                const int i = mt * 16 + kg * 4 + r;
                const int pos = l0 - 8 + i;
                float v0 = fmaxf(acc[mt][0][r] + bs0, 0.f);
                float v1 = fmaxf(acc[mt][1][r] + bs1, 0.f);
                if (pos < 0 || pos >= Ls) { v0 = 0.f; v1 = 0.f; }
                const int row = i;
                int a0 = row * 256 + (wv * 16 + nl) * 2;       a0 ^= SWZ(row);
                int a1 = row * 256 + ((wv + 4) * 16 + nl) * 2; a1 ^= SWZ(row);
                *(unsigned short*)(smem + a0) = f2bf(v0);
                *(unsigned short*)(smem + a1) = f2bf(v1);
            }
        }
    }
    __syncthreads();

    // ---- conv3 (dil 2): M=64, N=128, K=3 x 128 -> X3 bf16
    {
        f32x4 acc[4][2];
        #pragma unroll
        for (int mt = 0; mt < 4; ++mt) { acc[mt][0] = (f32x4)0.f; acc[mt][1] = (f32x4)0.f; }
        #pragma unroll
        for (int t = 0; t < 3; ++t) {
            #pragma unroll
            for (int kc = 0; kc < 4; ++kc) {
                const s16x8 bf0 = *(const s16x8*)(wfrag + (96 + (t * 4 + kc) * 8 + wv) * 64 + lane);
                const s16x8 bf1 = *(const s16x8*)(wfrag + (96 + (t * 4 + kc) * 8 + wv + 4) * 64 + lane);
                #pragma unroll
                for (int mt = 0; mt < 4; ++mt) {
                    const int row = 6 + mt * 16 + nl + 2 * t;
                    int addr = row * 256 + kc * 64 + kg * 16;
                    addr ^= SWZ(row);
                    const s16x8 a = *(const s16x8*)(smem + addr);
                    acc[mt][0] = __builtin_amdgcn_mfma_f32_16x16x32_bf16(a, bf0, acc[mt][0], 0, 0, 0);
                    acc[mt][1] = __builtin_amdgcn_mfma_f32_16x16x32_bf16(a, bf1, acc[mt][1], 0, 0, 0);
                }
            }
        }
        const float bs0 = b3[wv * 16 + nl], bs1 = b3[(wv + 4) * 16 + nl];
        #pragma unroll
        for (int mt = 0; mt < 4; ++mt) {
            #pragma unroll
            for (int r = 0; r < 4; ++r) {
                const int p = mt * 16 + kg * 4 + r;             // 0..63
                float v0 = fmaxf(acc[mt][0][r] + bs0, 0.f);
                float v1 = fmaxf(acc[mt][1][r] + bs1, 0.f);
                int a0 = X3_OFF + p * 256 + (wv * 16 + nl) * 2;       a0 ^= SWZ(p);
                int a1 = X3_OFF + p * 256 + ((wv + 4) * 16 + nl) * 2; a1 ^= SWZ(p);
                *(unsigned short*)(smem + a0) = f2bf(v0);
                *(unsigned short*)(smem + a1) = f2bf(v1);
            }
        }
    }
    __syncthreads();

    // ---- dense 128 -> 9 via MFMA; also writes transposed copy for CRF
    {
        f32x4 dacc = (f32x4)0.f;
        #pragma unroll
        for (int kc = 0; kc < 4; ++kc) {
            const int row = wv * 16 + nl;
            int addr = X3_OFF + row * 256 + kc * 64 + kg * 16;
            addr ^= SWZ(row);
            const s16x8 a = *(const s16x8*)(smem + addr);
            const s16x8 bf = *(const s16x8*)(wfrag + (192 + kc) * 64 + lane);
            dacc = __builtin_amdgcn_mfma_f32_16x16x32_bf16(a, bf, dacc, 0, 0, 0);
        }
        const float bdv = (nl < Kk) ? bd[nl] : 0.f;
        #pragma unroll
        for (int r = 0; r < 4; ++r) {
            const int p = wv * 16 + kg * 4 + r;
            if (nl < Kk) {
                const float val = dacc[r] + bdv;
                logits[((size_t)b * Ls + l0 + p) * Kk + nl] = val;
                logitsT[((size_t)(l0 + p) * Bb + b) * 12 + nl] = val;   // [t][row][12]
            }
        }
    }
}

// ---- CRF: linear-domain forward, one batch-row per lane, coalesced logitsT ----
#define STEP3(C0, C1, C2, t) { \
    float elg[9]; \
    elg[0]=__expf(C0.x); elg[1]=__expf(C0.y); elg[2]=__expf(C0.z); elg[3]=__expf(C0.w); \
    elg[4]=__expf(C1.x); elg[5]=__expf(C1.y); elg[6]=__expf(C1.z); elg[7]=__expf(C1.w); \
    elg[8]=__expf(C2.x); \
    float nf[9]; \
    _Pragma("unroll") for (int j_ = 0; j_ < 9; ++j_) { \
        float acc_ = f[0] * eT[j_]; \
        _Pragma("unroll") for (int i_ = 1; i_ < 9; ++i_) acc_ = fmaf(f[i_], eT[i_*9+j_], acc_); \
        nf[j_] = acc_ * elg[j_]; } \
    const bool keep_ = (t) < len; \
    _Pragma("unroll") for (int j_ = 0; j_ < 9; ++j_) f[j_] = keep_ ? nf[j_] : f[j_]; }

#define RENORM() { \
    float m_ = fmaxf(fmaxf(fmaxf(fmaxf(f[0],f[1]),fmaxf(f[2],f[3])),fmaxf(fmaxf(f[4],f[5]),fmaxf(f[6],f[7]))),f[8]); \
    C += __logf(m_); \
    const float inv_ = 1.0f / m_; \
    _Pragma("unroll") for (int j_ = 0; j_ < 9; ++j_) f[j_] *= inv_; }

__global__ __launch_bounds__(64, 1) void kc_crf(
    const int* __restrict__ text, const int* __restrict__ labels,
    const float* __restrict__ trans, const float* __restrict__ logits,
    const float4* __restrict__ logitsT4,
    float* __restrict__ lens_out, float* __restrict__ ll_out)
{
    const int blk = blockIdx.x;
    const int lane = threadIdx.x;
    __shared__ float trS[81];
    __shared__ int   lenI[64];
    __shared__ float scoreS[64];
    for (int i = lane; i < 81; i += 64) trS[i] = trans[i];
    __syncthreads();

    // Phase A: cooperative lens + sequence score
    for (int rl = 0; rl < 64; ++rl) {
        const int row = blk * 64 + rl;
        const int4 tx = ((const int4*)(text + (size_t)row * Ls))[lane];
        int c = (tx.x != 0) + (tx.y != 0) + (tx.z != 0) + (tx.w != 0);
        #pragma unroll
        for (int off = 1; off < 64; off <<= 1) c += __shfl_xor(c, off);
        const int len = c;
        const int4 lb = ((const int4*)(labels + (size_t)row * Ls))[lane];
        const int t0 = lane * 4;
        int la[5];
        la[0] = lb.x; la[1] = lb.y; la[2] = lb.z; la[3] = lb.w;
        la[4] = (t0 + 4 < Ls) ? labels[(size_t)row * Ls + t0 + 4] : 0;
        const float* lgrow = logits + (size_t)row * Ls * Kk;
        float s = 0.f;
        #pragma unroll
        for (int q = 0; q < 4; ++q) {
            const int t = t0 + q;
            if (t < len) s += lgrow[t * Kk + la[q]];
            if (t < len - 1) s += trS[la[q] * Kk + la[q + 1]];
        }
        #pragma unroll
        for (int off = 1; off < 64; off <<= 1) s += __shfl_xor(s, off);
        if (lane == 0) { lenI[rl] = len; scoreS[rl] = s; }
    }
    __syncthreads();

    // Phase B: one row per lane, all state in named registers.
    float eT[81];
    #pragma unroll
    for (int i = 0; i < 81; ++i) eT[i] = __expf(trS[i]);

    const int row = blk * 64 + lane;
    const int len = lenI[lane];
    const float score = scoreS[lane];
    lens_out[row] = (float)len;

    // logitsT4 index: (t*Bb + row)*3 + q  ; per-step stride 3*Bb float4s
    const float4* p = logitsT4 + (size_t)row * 3;
    #define LD(t, q) p[(size_t)(t) * (3 * Bb) + (q)]

    float f[9];
    float C = 0.f;
    {
        const float4 a0 = LD(0, 0), a1 = LD(0, 1), a2 = LD(0, 2);
        f[0]=__expf(a0.x); f[1]=__expf(a0.y); f[2]=__expf(a0.z); f[3]=__expf(a0.w);
        f[4]=__expf(a1.x); f[5]=__expf(a1.y); f[6]=__expf(a1.z); f[7]=__expf(a1.w);
        f[8]=__expf(a2.x);
    }
    float4 X0 = LD(1, 0), X1 = LD(1, 1), X2 = LD(1, 2);
    float4 Y0 = LD(2, 0), Y1 = LD(2, 1), Y2 = LD(2, 2);
    float4 Z0 = LD(3, 0), Z1 = LD(3, 1), Z2 = LD(3, 2);

    #pragma unroll 1
    for (int k = 0; k < 85; ++k) {
        const int t = 3 * k + 1;
        const int ta = (t + 3 <= 255) ? t + 3 : 255;
        const int tb = (t + 4 <= 255) ? t + 4 : 255;
        const int tc = (t + 5 <= 255) ? t + 5 : 255;
        float4 nX0 = LD(ta, 0), nX1 = LD(ta, 1), nX2 = LD(ta, 2);
        STEP3(X0, X1, X2, t)
        float4 nY0 = LD(tb, 0), nY1 = LD(tb, 1), nY2 = LD(tb, 2);
        STEP3(Y0, Y1, Y2, t + 1)
        float4 nZ0 = LD(tc, 0), nZ1 = LD(tc, 1), nZ2 = LD(tc, 2);
        STEP3(Z0, Z1, Z2, t + 2)
        RENORM()
        X0 = nX0; X1 = nX1; X2 = nX2;
        Y0 = nY0; Y1 = nY1; Y2 = nY2;
        Z0 = nZ0; Z1 = nZ1; Z2 = nZ2;
    }
    #undef LD

    float sum = f[0];
    #pragma unroll
    for (int j = 1; j < 9; ++j) sum += f[j];
    const float log_norm = C + __logf(sum);
    ll_out[row] = score - log_norm;
}

extern "C" void kernel_launch(void* const* d_in, const int* in_sizes, int n_in,
                              void* d_out, int out_size, void* d_ws, size_t ws_size,
                              hipStream_t stream) {
    const int*   text   = (const int*)d_in[0];
    const int*   labels = (const int*)d_in[1];
    const float* embed  = (const float*)d_in[2];
    const float* w1 = (const float*)d_in[3];
    const float* b1 = (const float*)d_in[4];
    const float* w2 = (const float*)d_in[5];
    const float* b2 = (const float*)d_in[6];
    const float* w3 = (const float*)d_in[7];
    const float* b3 = (const float*)d_in[8];
    const float* wd = (const float*)d_in[9];
    const float* bd = (const float*)d_in[10];
    const float* trans = (const float*)d_in[11];

    float* out      = (float*)d_out;
    float* logits   = out;
    float* lens_out = out + (size_t)Bb * Ls * Kk;
    float* ll_out   = lens_out + Bb;
    uint4* wfrag    = (uint4*)d_ws;                          // 196 KiB
    float* logitsT  = (float*)((char*)d_ws + 262144);        // [256][512][12] f32 = 6.3 MB

    hipLaunchKernelGGL(kw_prep, dim3(49), dim3(256), 0, stream, w1, w2, w3, wd, wfrag);
    hipLaunchKernelGGL(kmain, dim3(Ls / 64, Bb), dim3(256), 0, stream,
                       text, embed, wfrag, b1, b2, b3, bd, logits, logitsT);
    hipLaunchKernelGGL(kc_crf, dim3(Bb / 64), dim3(64), 0, stream,
                       text, labels, trans, logits, (const float4*)logitsT, lens_out, ll_out);
}

// Round 5
// 91.238 us; speedup vs baseline: 2.7460x; 2.7460x over previous
//
#include <hip/hip_runtime.h>
#include <hip/hip_bf16.h>

#define Ls 256
#define Kk 9
#define Bb 512

typedef short s16x8 __attribute__((ext_vector_type(8)));
typedef float f32x4 __attribute__((ext_vector_type(4)));

__device__ __forceinline__ unsigned short f2bf(float f) {
    __hip_bfloat16 h = __float2bfloat16(f);
    return *reinterpret_cast<unsigned short*>(&h);
}

// XOR swizzle: spreads 16 consecutive rows 2-way (free) on reads AND makes
// row-groups {c,c+4,c+8,c+12} (epilogue b16 stores) hit 4 distinct 16B slots.
#define SWZ(row) (((((row)&7)<<4)) ^ ((((row)&8))<<2))

// ---- weight prep: pack w1/w2/w3/wd into bf16 MFMA B-fragments ----
__global__ __launch_bounds__(256) void kw_prep(
    const float* __restrict__ w1, const float* __restrict__ w2, const float* __restrict__ w3,
    const float* __restrict__ wd, uint4* __restrict__ wfrag)
{
    const int gid = blockIdx.x * 256 + threadIdx.x;
    const int frag = gid >> 6;
    const int lane = gid & 63;
    if (frag >= 196) return;
    const int kb = (lane >> 4) * 8;
    const int nl = lane & 15;
    float v[8];
    if (frag < 48) {
        int nt = frag & 3, kc = (frag >> 2) & 3, t = frag >> 4;
        int n = nt * 16 + nl;
        #pragma unroll
        for (int j = 0; j < 8; ++j) v[j] = w1[(t * 128 + kc * 32 + kb + j) * 64 + n];
    } else if (frag < 96) {
        int f = frag - 48; int nt = f & 7, kc = (f >> 3) & 1, t = f >> 4;
        int n = nt * 16 + nl;
        #pragma unroll
        for (int j = 0; j < 8; ++j) v[j] = w2[(t * 64 + kc * 32 + kb + j) * 128 + n];
    } else if (frag < 192) {
        int f = frag - 96; int nt = f & 7, kc = (f >> 3) & 3, t = f >> 5;
        int n = nt * 16 + nl;
        #pragma unroll
        for (int j = 0; j < 8; ++j) v[j] = w3[(t * 128 + kc * 32 + kb + j) * 128 + n];
    } else {
        int kc = frag - 192;
        #pragma unroll
        for (int j = 0; j < 8; ++j) v[j] = (nl < Kk) ? wd[(kc * 32 + kb + j) * Kk + nl] : 0.f;
    }
    uint4 o;
    o.x = (unsigned)f2bf(v[0]) | ((unsigned)f2bf(v[1]) << 16);
    o.y = (unsigned)f2bf(v[2]) | ((unsigned)f2bf(v[3]) << 16);
    o.z = (unsigned)f2bf(v[4]) | ((unsigned)f2bf(v[5]) << 16);
    o.w = (unsigned)f2bf(v[6]) | ((unsigned)f2bf(v[7]) << 16);
    wfrag[frag * 64 + lane] = o;
}

// ---- fused embed + conv1 + conv2 + conv3(dil2) + dense(MFMA) ----
#define X1_OFF  20992
#define X3_OFF  20992
#define SMEM_BYTES (20992 + 64 * 256)   // 37376 -> 4 blocks/CU

__global__ __launch_bounds__(256, 4) void kmain(
    const int* __restrict__ text, const float* __restrict__ embed,
    const uint4* __restrict__ wfrag,
    const float* __restrict__ b1, const float* __restrict__ b2, const float* __restrict__ b3,
    const float* __restrict__ bd,
    float* __restrict__ logits)
{
    __shared__ __align__(16) char smem[SMEM_BYTES];
    const int b = blockIdx.y, l0 = blockIdx.x * 64;
    const int tid = threadIdx.x;
    const int lane = tid & 63, wv = tid >> 6;
    const int nl = lane & 15, kg = lane >> 4;

    for (int it = tid; it < 96; it += 256) {
        char* p;
        if (it < 32)       p = smem + it * 8;
        else if (it < 64)  p = smem + 81 * 256 + (it - 32) * 8;
        else if (it < 80)  p = smem + X1_OFF + (it - 64) * 8;
        else               p = smem + X1_OFF + 81 * 128 + (it - 80) * 8;
        *(uint2*)p = make_uint2(0u, 0u);
    }
    for (int it = tid; it < 80 * 32; it += 256) {
        const int row = (it >> 5) + 1;      // 1..80
        const int c4  = it & 31;
        const int pos = l0 - 9 + row;
        uint2 val = make_uint2(0u, 0u);
        if (pos >= 0 && pos < Ls) {
            const int tok = text[b * Ls + pos];
            const float4 e = ((const float4*)embed)[tok * 32 + c4];
            val.x = (unsigned)f2bf(e.x) | ((unsigned)f2bf(e.y) << 16);
            val.y = (unsigned)f2bf(e.z) | ((unsigned)f2bf(e.w) << 16);
        }
        int addr = row * 256 + c4 * 8;
        addr ^= SWZ(row);
        *(uint2*)(smem + addr) = val;
    }
    __syncthreads();

    // ---- conv1: M=80(5 tiles), N=64, K=3 x 128
    {
        f32x4 acc[5];
        #pragma unroll
        for (int mt = 0; mt < 5; ++mt) acc[mt] = (f32x4)0.f;
        #pragma unroll
        for (int t = 0; t < 3; ++t) {
            #pragma unroll
            for (int kc = 0; kc < 4; ++kc) {
                const s16x8 bf = *(const s16x8*)(wfrag + ((t * 4 + kc) * 4 + wv) * 64 + lane);
                #pragma unroll
                for (int mt = 0; mt < 5; ++mt) {
                    const int row = mt * 16 + nl + t;
                    int addr = row * 256 + kc * 64 + kg * 16;
                    addr ^= SWZ(row);
                    const s16x8 a = *(const s16x8*)(smem + addr);
                    acc[mt] = __builtin_amdgcn_mfma_f32_16x16x32_bf16(a, bf, acc[mt], 0, 0, 0);
                }
            }
        }
        const float bias = b1[wv * 16 + nl];
        #pragma unroll
        for (int mt = 0; mt < 5; ++mt) {
            #pragma unroll
            for (int r = 0; r < 4; ++r) {
                const int i = mt * 16 + kg * 4 + r;
                const int pos = l0 - 8 + i;
                float v = fmaxf(acc[mt][r] + bias, 0.f);
                if (pos < 0 || pos >= Ls) v = 0.f;
                const int row = i + 1;
                int addr = X1_OFF + row * 128 + (wv * 16 + nl) * 2;
                addr ^= SWZ(row);
                *(unsigned short*)(smem + addr) = f2bf(v);
            }
        }
    }
    __syncthreads();

    // ---- conv2: M=80, N=128, K=3 x 64
    {
        f32x4 acc[5][2];
        #pragma unroll
        for (int mt = 0; mt < 5; ++mt) { acc[mt][0] = (f32x4)0.f; acc[mt][1] = (f32x4)0.f; }
        #pragma unroll
        for (int t = 0; t < 3; ++t) {
            #pragma unroll
            for (int kc = 0; kc < 2; ++kc) {
                const s16x8 bf0 = *(const s16x8*)(wfrag + (48 + (t * 2 + kc) * 8 + wv) * 64 + lane);
                const s16x8 bf1 = *(const s16x8*)(wfrag + (48 + (t * 2 + kc) * 8 + wv + 4) * 64 + lane);
                #pragma unroll
                for (int mt = 0; mt < 5; ++mt) {
                    const int row = mt * 16 + nl + t;
                    int addr = X1_OFF + row * 128 + kc * 64 + kg * 16;
                    addr ^= SWZ(row);
                    const s16x8 a = *(const s16x8*)(smem + addr);
                    acc[mt][0] = __builtin_amdgcn_mfma_f32_16x16x32_bf16(a, bf0, acc[mt][0], 0, 0, 0);
                    acc[mt][1] = __builtin_amdgcn_mfma_f32_16x16x32_bf16(a, bf1, acc[mt][1], 0, 0, 0);
                }
            }
        }
        const float bs0 = b2[wv * 16 + nl], bs1 = b2[(wv + 4) * 16 + nl];
        #pragma unroll
        for (int mt = 0; mt < 5; ++mt) {
            #pragma unroll
            for (int r = 0; r < 4; ++r) {
                const int i = mt * 16 + kg * 4 + r;
                const int pos = l0 - 8 + i;
                float v0 = fmaxf(acc[mt][0][r] + bs0, 0.f);
                float v1 = fmaxf(acc[mt][1][r] + bs1, 0.f);
                if (pos < 0 || pos >= Ls) { v0 = 0.f; v1 = 0.f; }
                const int row = i;
                int a0 = row * 256 + (wv * 16 + nl) * 2;       a0 ^= SWZ(row);
                int a1 = row * 256 + ((wv + 4) * 16 + nl) * 2; a1 ^= SWZ(row);
                *(unsigned short*)(smem + a0) = f2bf(v0);
                *(unsigned short*)(smem + a1) = f2bf(v1);
            }
        }
    }
    __syncthreads();

    // ---- conv3 (dil 2): M=64, N=128, K=3 x 128 -> X3 bf16
    {
        f32x4 acc[4][2];
        #pragma unroll
        for (int mt = 0; mt < 4; ++mt) { acc[mt][0] = (f32x4)0.f; acc[mt][1] = (f32x4)0.f; }
        #pragma unroll
        for (int t = 0; t < 3; ++t) {
            #pragma unroll
            for (int kc = 0; kc < 4; ++kc) {
                const s16x8 bf0 = *(const s16x8*)(wfrag + (96 + (t * 4 + kc) * 8 + wv) * 64 + lane);
                const s16x8 bf1 = *(const s16x8*)(wfrag + (96 + (t * 4 + kc) * 8 + wv + 4) * 64 + lane);
                #pragma unroll
                for (int mt = 0; mt < 4; ++mt) {
                    const int row = 6 + mt * 16 + nl + 2 * t;
                    int addr = row * 256 + kc * 64 + kg * 16;
                    addr ^= SWZ(row);
                    const s16x8 a = *(const s16x8*)(smem + addr);
                    acc[mt][0] = __builtin_amdgcn_mfma_f32_16x16x32_bf16(a, bf0, acc[mt][0], 0, 0, 0);
                    acc[mt][1] = __builtin_amdgcn_mfma_f32_16x16x32_bf16(a, bf1, acc[mt][1], 0, 0, 0);
                }
            }
        }
        const float bs0 = b3[wv * 16 + nl], bs1 = b3[(wv + 4) * 16 + nl];
        #pragma unroll
        for (int mt = 0; mt < 4; ++mt) {
            #pragma unroll
            for (int r = 0; r < 4; ++r) {
                const int p = mt * 16 + kg * 4 + r;             // 0..63
                float v0 = fmaxf(acc[mt][0][r] + bs0, 0.f);
                float v1 = fmaxf(acc[mt][1][r] + bs1, 0.f);
                int a0 = X3_OFF + p * 256 + (wv * 16 + nl) * 2;       a0 ^= SWZ(p);
                int a1 = X3_OFF + p * 256 + ((wv + 4) * 16 + nl) * 2; a1 ^= SWZ(p);
                *(unsigned short*)(smem + a0) = f2bf(v0);
                *(unsigned short*)(smem + a1) = f2bf(v1);
            }
        }
    }
    __syncthreads();

    // ---- dense 128 -> 9 via MFMA
    {
        f32x4 dacc = (f32x4)0.f;
        #pragma unroll
        for (int kc = 0; kc < 4; ++kc) {
            const int row = wv * 16 + nl;
            int addr = X3_OFF + row * 256 + kc * 64 + kg * 16;
            addr ^= SWZ(row);
            const s16x8 a = *(const s16x8*)(smem + addr);
            const s16x8 bf = *(const s16x8*)(wfrag + (192 + kc) * 64 + lane);
            dacc = __builtin_amdgcn_mfma_f32_16x16x32_bf16(a, bf, dacc, 0, 0, 0);
        }
        const float bdv = (nl < Kk) ? bd[nl] : 0.f;
        #pragma unroll
        for (int r = 0; r < 4; ++r) {
            const int p = wv * 16 + kg * 4 + r;
            if (nl < Kk)
                logits[((size_t)b * Ls + l0 + p) * Kk + nl] = dacc[r] + bdv;
        }
    }
}

// ---- CRF: one wave per batch row; state j on lane j; linear domain ----
// lane j<9: f = alpha_j (linear, scaled), col[i] = exp(trans[i][j]); lanes >=9: f=0,col=0.
#define MN(x) (((x) < 255) ? (x) : 255)

#define CSTEP(LG, t) { \
    float p0 = __shfl(f, 0) * col[0]; \
    float p1 = __shfl(f, 1) * col[1]; \
    float p2 = __shfl(f, 2) * col[2]; \
    float p3 = __shfl(f, 3) * col[3]; \
    float p4 = __shfl(f, 4) * col[4]; \
    float p5 = __shfl(f, 5) * col[5]; \
    float p6 = __shfl(f, 6) * col[6]; \
    float p7 = __shfl(f, 7) * col[7]; \
    float p8 = __shfl(f, 8) * col[8]; \
    float s_ = ((p0 + p1) + (p2 + p3)) + ((p4 + p5) + (p6 + p7)) + p8; \
    float nf_ = __expf(LG) * s_; \
    f = ((t) < len) ? nf_ : f; }

#define RN() { \
    float m_ = f; \
    m_ = fmaxf(m_, __shfl_xor(m_, 1, 16)); \
    m_ = fmaxf(m_, __shfl_xor(m_, 2, 16)); \
    m_ = fmaxf(m_, __shfl_xor(m_, 4, 16)); \
    m_ = fmaxf(m_, __shfl_xor(m_, 8, 16)); \
    C += __logf(m_); \
    f *= (1.0f / m_); }

__global__ __launch_bounds__(64) void kc_crf(
    const int* __restrict__ text, const int* __restrict__ labels,
    const float* __restrict__ trans, const float* __restrict__ logits,
    float* __restrict__ lens_out, float* __restrict__ ll_out)
{
    const int row = blockIdx.x;
    const int lane = threadIdx.x;
    __shared__ float trS[81];
    for (int i = lane; i < 81; i += 64) trS[i] = trans[i];
    __syncthreads();

    // ---- Phase A: lens + sequence score (all 64 lanes)
    const int4 tx = ((const int4*)(text + (size_t)row * Ls))[lane];
    int c = (tx.x != 0) + (tx.y != 0) + (tx.z != 0) + (tx.w != 0);
    #pragma unroll
    for (int off = 1; off < 64; off <<= 1) c += __shfl_xor(c, off);
    const int len = c;
    if (lane == 0) lens_out[row] = (float)len;

    const int4 lb = ((const int4*)(labels + (size_t)row * Ls))[lane];
    const int t0 = lane * 4;
    int la[5];
    la[0] = lb.x; la[1] = lb.y; la[2] = lb.z; la[3] = lb.w;
    la[4] = (t0 + 4 < Ls) ? labels[(size_t)row * Ls + t0 + 4] : 0;
    const float* lgrow = logits + (size_t)row * Ls * Kk;
    float sc = 0.f;
    #pragma unroll
    for (int q = 0; q < 4; ++q) {
        const int t = t0 + q;
        if (t < len) sc += lgrow[t * Kk + la[q]];
        if (t < len - 1) sc += trS[la[q] * Kk + la[q + 1]];
    }
    #pragma unroll
    for (int off = 1; off < 64; off <<= 1) sc += __shfl_xor(sc, off);
    const float score = sc;

    // ---- Phase B: forward recurrence, state j on lane j
    const int j = (lane < Kk) ? lane : 0;
    const bool act = (lane < Kk);
    float col[9];
    #pragma unroll
    for (int i = 0; i < 9; ++i) col[i] = act ? __expf(trS[i * Kk + j]) : 0.f;

    const float* lp = lgrow + j;
    float f = act ? __expf(lp[0]) : 0.f;
    float C = 0.f;

    // prefetch t=1..8
    float a0 = lp[9 * 1], a1 = lp[9 * 2], a2 = lp[9 * 3], a3 = lp[9 * 4];
    float a4 = lp[9 * 5], a5 = lp[9 * 6], a6 = lp[9 * 7], a7 = lp[9 * 8];

    #pragma unroll 1
    for (int kk = 0; kk < 32; ++kk) {
        const int nb = 8 * kk + 9;
        const float b0 = lp[9 * MN(nb + 0)], b1 = lp[9 * MN(nb + 1)];
        const float b2 = lp[9 * MN(nb + 2)], b3 = lp[9 * MN(nb + 3)];
        const float b4 = lp[9 * MN(nb + 4)], b5 = lp[9 * MN(nb + 5)];
        const float b6 = lp[9 * MN(nb + 6)], b7 = lp[9 * MN(nb + 7)];
        const int tb = 8 * kk;
        CSTEP(a0, tb + 1) CSTEP(a1, tb + 2) CSTEP(a2, tb + 3) CSTEP(a3, tb + 4)
        CSTEP(a4, tb + 5) CSTEP(a5, tb + 6) CSTEP(a6, tb + 7) CSTEP(a7, tb + 8)
        RN()
        a0 = b0; a1 = b1; a2 = b2; a3 = b3;
        a4 = b4; a5 = b5; a6 = b6; a7 = b7;
    }

    float sum = f;
    sum += __shfl_xor(sum, 1, 16);
    sum += __shfl_xor(sum, 2, 16);
    sum += __shfl_xor(sum, 4, 16);
    sum += __shfl_xor(sum, 8, 16);
    if (lane == 0) ll_out[row] = score - (C + __logf(sum));
}

extern "C" void kernel_launch(void* const* d_in, const int* in_sizes, int n_in,
                              void* d_out, int out_size, void* d_ws, size_t ws_size,
                              hipStream_t stream) {
    const int*   text   = (const int*)d_in[0];
    const int*   labels = (const int*)d_in[1];
    const float* embed  = (const float*)d_in[2];
    const float* w1 = (const float*)d_in[3];
    const float* b1 = (const float*)d_in[4];
    const float* w2 = (const float*)d_in[5];
    const float* b2 = (const float*)d_in[6];
    const float* w3 = (const float*)d_in[7];
    const float* b3 = (const float*)d_in[8];
    const float* wd = (const float*)d_in[9];
    const float* bd = (const float*)d_in[10];
    const float* trans = (const float*)d_in[11];

    float* out      = (float*)d_out;
    float* logits   = out;
    float* lens_out = out + (size_t)Bb * Ls * Kk;
    float* ll_out   = lens_out + Bb;
    uint4* wfrag    = (uint4*)d_ws;     // 196 KiB

    hipLaunchKernelGGL(kw_prep, dim3(49), dim3(256), 0, stream, w1, w2, w3, wd, wfrag);
    hipLaunchKernelGGL(kmain, dim3(Ls / 64, Bb), dim3(256), 0, stream,
                       text, embed, wfrag, b1, b2, b3, bd, logits);
    hipLaunchKernelGGL(kc_crf, dim3(Bb), dim3(64), 0, stream,
                       text, labels, trans, logits, lens_out, ll_out);
}

// Round 6
// 78.285 us; speedup vs baseline: 3.2004x; 1.1655x over previous
//
#include <hip/hip_runtime.h>
#include <hip/hip_bf16.h>

#define Ls 256
#define Kk 9
#define Bb 512

typedef short s16x8 __attribute__((ext_vector_type(8)));
typedef float f32x4 __attribute__((ext_vector_type(4)));

__device__ __forceinline__ unsigned short f2bf(float f) {
    __hip_bfloat16 h = __float2bfloat16(f);
    return *reinterpret_cast<unsigned short*>(&h);
}
__device__ __forceinline__ unsigned pk2bf(float a, float b) {
    __hip_bfloat162 h = __float22bfloat162_rn(make_float2(a, b));
    return *reinterpret_cast<unsigned*>(&h);
}

// XOR swizzle on byte addr bits 4-6, function of row&15 only.
#define SWZ(row) (((((row)&7)<<4)) ^ ((((row)&8))<<2))

// ---- weight prep: pack w1/w2/w3/wd into bf16 MFMA fragments ----
// lane l of frag: k = kc*32 + (l>>4)*8 + j , n = nt*16 + (l&15).
__global__ __launch_bounds__(256) void kw_prep(
    const float* __restrict__ w1, const float* __restrict__ w2, const float* __restrict__ w3,
    const float* __restrict__ wd, uint4* __restrict__ wfrag)
{
    const int gid = blockIdx.x * 256 + threadIdx.x;
    const int frag = gid >> 6;
    const int lane = gid & 63;
    if (frag >= 196) return;
    const int kb = (lane >> 4) * 8;
    const int nl = lane & 15;
    float v[8];
    if (frag < 48) {
        int nt = frag & 3, kc = (frag >> 2) & 3, t = frag >> 4;
        int n = nt * 16 + nl;
        #pragma unroll
        for (int j = 0; j < 8; ++j) v[j] = w1[(t * 128 + kc * 32 + kb + j) * 64 + n];
    } else if (frag < 96) {
        int f = frag - 48; int nt = f & 7, kc = (f >> 3) & 1, t = f >> 4;
        int n = nt * 16 + nl;
        #pragma unroll
        for (int j = 0; j < 8; ++j) v[j] = w2[(t * 64 + kc * 32 + kb + j) * 128 + n];
    } else if (frag < 192) {
        int f = frag - 96; int nt = f & 7, kc = (f >> 3) & 3, t = f >> 5;
        int n = nt * 16 + nl;
        #pragma unroll
        for (int j = 0; j < 8; ++j) v[j] = w3[(t * 128 + kc * 32 + kb + j) * 128 + n];
    } else {
        int kc = frag - 192;
        #pragma unroll
        for (int j = 0; j < 8; ++j) v[j] = (nl < Kk) ? wd[(kc * 32 + kb + j) * Kk + nl] : 0.f;
    }
    uint4 o;
    o.x = (unsigned)f2bf(v[0]) | ((unsigned)f2bf(v[1]) << 16);
    o.y = (unsigned)f2bf(v[2]) | ((unsigned)f2bf(v[3]) << 16);
    o.z = (unsigned)f2bf(v[4]) | ((unsigned)f2bf(v[5]) << 16);
    o.w = (unsigned)f2bf(v[6]) | ((unsigned)f2bf(v[7]) << 16);
    wfrag[frag * 64 + lane] = o;
}

// ---- fused embed + conv1 + conv2 + conv3(dil2) + dense(MFMA) ----
// E  (bf16, 82 rows x 256B, row = i+1)  aliased by X2 (80 rows x 256B, row = i)
// X1 (bf16, 82 rows x 128B, row = i+1)  aliased by X3 (bf16, 64 rows x 256B, row = p)
#define X1_OFF  20992
#define X3_OFF  20992
#define SMEM_BYTES (20992 + 64 * 256)   // 37376 -> 4 blocks/CU

__global__ __launch_bounds__(256, 4) void kmain(
    const int* __restrict__ text, const float* __restrict__ embed,
    const uint4* __restrict__ wfrag,
    const float* __restrict__ b1, const float* __restrict__ b2, const float* __restrict__ b3,
    const float* __restrict__ bd,
    float* __restrict__ logits)
{
    __shared__ __align__(16) char smem[SMEM_BYTES];
    const int b = blockIdx.y, l0 = blockIdx.x * 64;
    const int tid = threadIdx.x;
    const int lane = tid & 63, wv = tid >> 6;
    const int nl = lane & 15, kg = lane >> 4;

    // zero pad rows: E rows 0,81 ; X1 rows 0,81
    for (int it = tid; it < 96; it += 256) {
        char* p;
        if (it < 32)       p = smem + it * 8;
        else if (it < 64)  p = smem + 81 * 256 + (it - 32) * 8;
        else if (it < 80)  p = smem + X1_OFF + (it - 64) * 8;
        else               p = smem + X1_OFF + 81 * 128 + (it - 80) * 8;
        *(uint2*)p = make_uint2(0u, 0u);
    }
    // stage embed rows (pos l0-8 .. l0+71) as bf16, swizzled; rows 1..80
    {
        const int g = tid >> 5, c4 = tid & 31;
        const int sbase = (((1 + g) * 256 + c4 * 8) ^ SWZ(1 + g));
        const int posb = l0 - 8 + g;          // pos of row (1+g) at it=0
        #pragma unroll
        for (int it = 0; it < 10; ++it) {
            const int pos = posb + it * 8;
            uint2 val = make_uint2(0u, 0u);
            if (pos >= 0 && pos < Ls) {
                const int tok = text[b * Ls + pos];
                const float4 e = ((const float4*)embed)[tok * 32 + c4];
                val.x = pk2bf(e.x, e.y);
                val.y = pk2bf(e.z, e.w);
            }
            const int addr = (sbase + it * 2048) ^ ((it & 1) << 5);
            *(uint2*)(smem + addr) = val;
        }
    }
    __syncthreads();

    // ---- conv1 (swapped): D[chan][pos], M=64 chans (tile wv), N=80 pos (5 tiles), K=3x128
    {
        const float4 bz = *(const float4*)(b1 + wv * 16 + kg * 4);
        f32x4 acc[5];
        #pragma unroll
        for (int nt = 0; nt < 5; ++nt) { acc[nt][0]=bz.x; acc[nt][1]=bz.y; acc[nt][2]=bz.z; acc[nt][3]=bz.w; }
        int xb[3][4];
        #pragma unroll
        for (int t = 0; t < 3; ++t)
            #pragma unroll
            for (int kc = 0; kc < 4; ++kc)
                xb[t][kc] = (((nl + t) * 256 + kc * 64 + kg * 16) ^ SWZ(nl + t));
        #pragma unroll
        for (int t = 0; t < 3; ++t) {
            #pragma unroll
            for (int kc = 0; kc < 4; ++kc) {
                const s16x8 wf = *(const s16x8*)(wfrag + ((t * 4 + kc) * 4 + wv) * 64 + lane);
                #pragma unroll
                for (int nt = 0; nt < 5; ++nt) {
                    const s16x8 a = *(const s16x8*)(smem + xb[t][kc] + nt * 4096);
                    acc[nt] = __builtin_amdgcn_mfma_f32_16x16x32_bf16(wf, a, acc[nt], 0, 0, 0);
                }
            }
        }
        const int wb = (X1_OFF + (nl + 1) * 128 + (wv * 16 + kg * 4) * 2) ^ SWZ(nl + 1);
        #pragma unroll
        for (int nt = 0; nt < 5; ++nt) {
            const int pos = l0 - 8 + nt * 16 + nl;
            const bool ok = (pos >= 0) && (pos < Ls);
            uint2 pk;
            pk.x = ok ? pk2bf(fmaxf(acc[nt][0], 0.f), fmaxf(acc[nt][1], 0.f)) : 0u;
            pk.y = ok ? pk2bf(fmaxf(acc[nt][2], 0.f), fmaxf(acc[nt][3], 0.f)) : 0u;
            *(uint2*)(smem + wb + nt * 2048) = pk;
        }
    }
    __syncthreads();

    // ---- conv2 (swapped): M=128 chans (tiles wv, wv+4), N=80 pos, K=3x64
    {
        const float4 bz0 = *(const float4*)(b2 + wv * 16 + kg * 4);
        const float4 bz1 = *(const float4*)(b2 + wv * 16 + 64 + kg * 4);
        f32x4 acc0[5], acc1[5];
        #pragma unroll
        for (int nt = 0; nt < 5; ++nt) {
            acc0[nt][0]=bz0.x; acc0[nt][1]=bz0.y; acc0[nt][2]=bz0.z; acc0[nt][3]=bz0.w;
            acc1[nt][0]=bz1.x; acc1[nt][1]=bz1.y; acc1[nt][2]=bz1.z; acc1[nt][3]=bz1.w;
        }
        int xb[3][2];
        #pragma unroll
        for (int t = 0; t < 3; ++t)
            #pragma unroll
            for (int kc = 0; kc < 2; ++kc)
                xb[t][kc] = ((X1_OFF + (nl + t) * 128 + kc * 64 + kg * 16) ^ SWZ(nl + t));
        #pragma unroll
        for (int t = 0; t < 3; ++t) {
            #pragma unroll
            for (int kc = 0; kc < 2; ++kc) {
                const s16x8 wf0 = *(const s16x8*)(wfrag + (48 + (t * 2 + kc) * 8 + wv) * 64 + lane);
                const s16x8 wf1 = *(const s16x8*)(wfrag + (48 + (t * 2 + kc) * 8 + wv + 4) * 64 + lane);
                #pragma unroll
                for (int nt = 0; nt < 5; ++nt) {
                    const s16x8 a = *(const s16x8*)(smem + xb[t][kc] + nt * 2048);
                    acc0[nt] = __builtin_amdgcn_mfma_f32_16x16x32_bf16(wf0, a, acc0[nt], 0, 0, 0);
                    acc1[nt] = __builtin_amdgcn_mfma_f32_16x16x32_bf16(wf1, a, acc1[nt], 0, 0, 0);
                }
            }
        }
        const int wb0 = (nl * 256 + (wv * 16 + kg * 4) * 2) ^ SWZ(nl);
        const int wb1 = (nl * 256 + (wv * 16 + 64 + kg * 4) * 2) ^ SWZ(nl);
        #pragma unroll
        for (int nt = 0; nt < 5; ++nt) {
            const int pos = l0 - 8 + nt * 16 + nl;
            const bool ok = (pos >= 0) && (pos < Ls);
            uint2 pa, pb;
            pa.x = ok ? pk2bf(fmaxf(acc0[nt][0], 0.f), fmaxf(acc0[nt][1], 0.f)) : 0u;
            pa.y = ok ? pk2bf(fmaxf(acc0[nt][2], 0.f), fmaxf(acc0[nt][3], 0.f)) : 0u;
            pb.x = ok ? pk2bf(fmaxf(acc1[nt][0], 0.f), fmaxf(acc1[nt][1], 0.f)) : 0u;
            pb.y = ok ? pk2bf(fmaxf(acc1[nt][2], 0.f), fmaxf(acc1[nt][3], 0.f)) : 0u;
            *(uint2*)(smem + wb0 + nt * 4096) = pa;
            *(uint2*)(smem + wb1 + nt * 4096) = pb;
        }
    }
    __syncthreads();

    // ---- conv3 (dil 2, swapped): M=128 chans (wv, wv+4), N=64 pos (4 tiles), K=3x128
    {
        const float4 bz0 = *(const float4*)(b3 + wv * 16 + kg * 4);
        const float4 bz1 = *(const float4*)(b3 + wv * 16 + 64 + kg * 4);
        f32x4 acc0[4], acc1[4];
        #pragma unroll
        for (int nt = 0; nt < 4; ++nt) {
            acc0[nt][0]=bz0.x; acc0[nt][1]=bz0.y; acc0[nt][2]=bz0.z; acc0[nt][3]=bz0.w;
            acc1[nt][0]=bz1.x; acc1[nt][1]=bz1.y; acc1[nt][2]=bz1.z; acc1[nt][3]=bz1.w;
        }
        int xb[3][4];
        #pragma unroll
        for (int t = 0; t < 3; ++t)
            #pragma unroll
            for (int kc = 0; kc < 4; ++kc) {
                const int q = nl + 6 + 2 * t;       // X2 row for nt=0
                xb[t][kc] = ((q * 256 + kc * 64 + kg * 16) ^ SWZ(q));
            }
        #pragma unroll
        for (int t = 0; t < 3; ++t) {
            #pragma unroll
            for (int kc = 0; kc < 4; ++kc) {
                const s16x8 wf0 = *(const s16x8*)(wfrag + (96 + (t * 4 + kc) * 8 + wv) * 64 + lane);
                const s16x8 wf1 = *(const s16x8*)(wfrag + (96 + (t * 4 + kc) * 8 + wv + 4) * 64 + lane);
                #pragma unroll
                for (int nt = 0; nt < 4; ++nt) {
                    const s16x8 a = *(const s16x8*)(smem + xb[t][kc] + nt * 4096);
                    acc0[nt] = __builtin_amdgcn_mfma_f32_16x16x32_bf16(wf0, a, acc0[nt], 0, 0, 0);
                    acc1[nt] = __builtin_amdgcn_mfma_f32_16x16x32_bf16(wf1, a, acc1[nt], 0, 0, 0);
                }
            }
        }
        const int wb0 = (X3_OFF + nl * 256 + (wv * 16 + kg * 4) * 2) ^ SWZ(nl);
        const int wb1 = (X3_OFF + nl * 256 + (wv * 16 + 64 + kg * 4) * 2) ^ SWZ(nl);
        #pragma unroll
        for (int nt = 0; nt < 4; ++nt) {     // all 64 positions in-range: no mask
            uint2 pa, pb;
            pa.x = pk2bf(fmaxf(acc0[nt][0], 0.f), fmaxf(acc0[nt][1], 0.f));
            pa.y = pk2bf(fmaxf(acc0[nt][2], 0.f), fmaxf(acc0[nt][3], 0.f));
            pb.x = pk2bf(fmaxf(acc1[nt][0], 0.f), fmaxf(acc1[nt][1], 0.f));
            pb.y = pk2bf(fmaxf(acc1[nt][2], 0.f), fmaxf(acc1[nt][3], 0.f));
            *(uint2*)(smem + wb0 + nt * 4096) = pa;
            *(uint2*)(smem + wb1 + nt * 4096) = pb;
        }
    }
    __syncthreads();

    // ---- dense 128 -> 9 via MFMA (unswapped: D[pos][k]); bias via acc init
    {
        const float bdv = (nl < Kk) ? bd[nl] : 0.f;
        f32x4 dacc;
        dacc[0] = bdv; dacc[1] = bdv; dacc[2] = bdv; dacc[3] = bdv;
        #pragma unroll
        for (int kc = 0; kc < 4; ++kc) {
            const int ad = (X3_OFF + (wv * 16 + nl) * 256 + kc * 64 + kg * 16) ^ SWZ(nl);
            const s16x8 a = *(const s16x8*)(smem + ad);
            const s16x8 wf = *(const s16x8*)(wfrag + (192 + kc) * 64 + lane);
            dacc = __builtin_amdgcn_mfma_f32_16x16x32_bf16(a, wf, dacc, 0, 0, 0);
        }
        if (nl < Kk) {
            #pragma unroll
            for (int r = 0; r < 4; ++r) {
                const int p = wv * 16 + kg * 4 + r;
                logits[((size_t)b * Ls + l0 + p) * Kk + nl] = dacc[r];
            }
        }
    }
}

// ---- CRF: one wave per batch row; state j on lane j; linear domain ----
#define MN(x) (((x) < 255) ? (x) : 255)
#define RDL(i) __int_as_float(__builtin_amdgcn_readlane(__float_as_int(f), (i)))

#define CSTEP(LG, t) { \
    const float p0 = RDL(0) * col[0]; \
    const float p1 = RDL(1) * col[1]; \
    const float p2 = RDL(2) * col[2]; \
    const float p3 = RDL(3) * col[3]; \
    const float p4 = RDL(4) * col[4]; \
    const float p5 = RDL(5) * col[5]; \
    const float p6 = RDL(6) * col[6]; \
    const float p7 = RDL(7) * col[7]; \
    const float p8 = RDL(8) * col[8]; \
    const float s_ = ((p0 + p1) + (p2 + p3)) + ((p4 + p5) + (p6 + p7)) + p8; \
    const float nf_ = __expf(LG) * s_; \
    f = ((t) < len) ? nf_ : f; }

#define RN() { \
    float m_ = f; \
    m_ = fmaxf(m_, __shfl_xor(m_, 1, 16)); \
    m_ = fmaxf(m_, __shfl_xor(m_, 2, 16)); \
    m_ = fmaxf(m_, __shfl_xor(m_, 4, 16)); \
    m_ = fmaxf(m_, __shfl_xor(m_, 8, 16)); \
    C += __logf(m_); \
    f *= (1.0f / m_); }

__global__ __launch_bounds__(64) void kc_crf(
    const int* __restrict__ text, const int* __restrict__ labels,
    const float* __restrict__ trans, const float* __restrict__ logits,
    float* __restrict__ lens_out, float* __restrict__ ll_out)
{
    const int row = blockIdx.x;
    const int lane = threadIdx.x;
    __shared__ float trS[81];
    for (int i = lane; i < 81; i += 64) trS[i] = trans[i];
    __syncthreads();

    // ---- Phase A: lens + sequence score (all 64 lanes)
    const int4 tx = ((const int4*)(text + (size_t)row * Ls))[lane];
    int c = (tx.x != 0) + (tx.y != 0) + (tx.z != 0) + (tx.w != 0);
    #pragma unroll
    for (int off = 1; off < 64; off <<= 1) c += __shfl_xor(c, off);
    const int len = c;
    if (lane == 0) lens_out[row] = (float)len;

    const int4 lb = ((const int4*)(labels + (size_t)row * Ls))[lane];
    const int t0 = lane * 4;
    int la[5];
    la[0] = lb.x; la[1] = lb.y; la[2] = lb.z; la[3] = lb.w;
    la[4] = (t0 + 4 < Ls) ? labels[(size_t)row * Ls + t0 + 4] : 0;
    const float* lgrow = logits + (size_t)row * Ls * Kk;
    float sc = 0.f;
    #pragma unroll
    for (int q = 0; q < 4; ++q) {
        const int t = t0 + q;
        if (t < len) sc += lgrow[t * Kk + la[q]];
        if (t < len - 1) sc += trS[la[q] * Kk + la[q + 1]];
    }
    #pragma unroll
    for (int off = 1; off < 64; off <<= 1) sc += __shfl_xor(sc, off);
    const float score = sc;

    // ---- Phase B: forward recurrence, state j on lane j
    const int j = (lane < Kk) ? lane : 0;
    const bool act = (lane < Kk);
    float col[9];
    #pragma unroll
    for (int i = 0; i < 9; ++i) col[i] = act ? __expf(trS[i * Kk + j]) : 0.f;

    const float* lp = lgrow + j;
    float f = act ? __expf(lp[0]) : 0.f;
    float C = 0.f;

    // prefetch t=1..8
    float a0 = lp[9 * 1], a1 = lp[9 * 2], a2 = lp[9 * 3], a3 = lp[9 * 4];
    float a4 = lp[9 * 5], a5 = lp[9 * 6], a6 = lp[9 * 7], a7 = lp[9 * 8];

    #pragma unroll 1
    for (int kk = 0; kk < 32; ++kk) {
        const int nb = 8 * kk + 9;
        const float b0 = lp[9 * MN(nb + 0)], b1 = lp[9 * MN(nb + 1)];
        const float b2 = lp[9 * MN(nb + 2)], b3 = lp[9 * MN(nb + 3)];
        const float b4 = lp[9 * MN(nb + 4)], b5 = lp[9 * MN(nb + 5)];
        const float b6 = lp[9 * MN(nb + 6)], b7 = lp[9 * MN(nb + 7)];
        const int tb = 8 * kk;
        CSTEP(a0, tb + 1) CSTEP(a1, tb + 2) CSTEP(a2, tb + 3) CSTEP(a3, tb + 4)
        CSTEP(a4, tb + 5) CSTEP(a5, tb + 6) CSTEP(a6, tb + 7) CSTEP(a7, tb + 8)
        RN()
        a0 = b0; a1 = b1; a2 = b2; a3 = b3;
        a4 = b4; a5 = b5; a6 = b6; a7 = b7;
    }

    float sum = f;
    sum += __shfl_xor(sum, 1, 16);
    sum += __shfl_xor(sum, 2, 16);
    sum += __shfl_xor(sum, 4, 16);
    sum += __shfl_xor(sum, 8, 16);
    if (lane == 0) ll_out[row] = score - (C + __logf(sum));
}

extern "C" void kernel_launch(void* const* d_in, const int* in_sizes, int n_in,
                              void* d_out, int out_size, void* d_ws, size_t ws_size,
                              hipStream_t stream) {
    const int*   text   = (const int*)d_in[0];
    const int*   labels = (const int*)d_in[1];
    const float* embed  = (const float*)d_in[2];
    const float* w1 = (const float*)d_in[3];
    const float* b1 = (const float*)d_in[4];
    const float* w2 = (const float*)d_in[5];
    const float* b2 = (const float*)d_in[6];
    const float* w3 = (const float*)d_in[7];
    const float* b3 = (const float*)d_in[8];
    const float* wd = (const float*)d_in[9];
    const float* bd = (const float*)d_in[10];
    const float* trans = (const float*)d_in[11];

    float* out      = (float*)d_out;
    float* logits   = out;
    float* lens_out = out + (size_t)Bb * Ls * Kk;
    float* ll_out   = lens_out + Bb;
    uint4* wfrag    = (uint4*)d_ws;     // 196 KiB

    hipLaunchKernelGGL(kw_prep, dim3(49), dim3(256), 0, stream, w1, w2, w3, wd, wfrag);
    hipLaunchKernelGGL(kmain, dim3(Ls / 64, Bb), dim3(256), 0, stream,
                       text, embed, wfrag, b1, b2, b3, bd, logits);
    hipLaunchKernelGGL(kc_crf, dim3(Bb), dim3(64), 0, stream,
                       text, labels, trans, logits, lens_out, ll_out);
}